// Round 9
// baseline (526.624 us; speedup 1.0000x reference)
//
#include <hip/hip_runtime.h>
#include <math.h>

// ---------------------------------------------------------------------------
// N=50000 nodes, E=800000 edges (+N self-loops), IN=256, HID=128, OUT=128.
// GEMMs: bf16 MFMA 16x16x32, alpha (attention logits) fused into epilogue.
// GAT: fused softmax+aggregation, x4-unrolled gather.  No cooperative launch.
// ---------------------------------------------------------------------------

#define NEG_SLOPE 0.2f
#define EPS_DEN 1e-16f

typedef __attribute__((ext_vector_type(8))) short short8;
typedef __attribute__((ext_vector_type(4))) float f32x4;
typedef __attribute__((ext_vector_type(4))) unsigned short u16x4;

__device__ inline unsigned short f2b(float f) {  // RNE float->bf16
  unsigned u = __builtin_bit_cast(unsigned, f);
  unsigned r = (u + 0x7fffu + ((u >> 16) & 1u)) >> 16;
  return (unsigned short)r;
}
__device__ inline float b2f(unsigned short u) {
  return __builtin_bit_cast(float, (unsigned)u << 16);
}

__device__ inline void glds16(const void* g, void* l) {
  __builtin_amdgcn_global_load_lds(
      (const __attribute__((address_space(1))) void*)g,
      (__attribute__((address_space(3))) void*)l, 16, 0, 0);
}

template <int H>
__device__ inline void loadH(const float* p, float* v) {
  if constexpr (H == 4) {
    float4 t = *(const float4*)p;
    v[0] = t.x; v[1] = t.y; v[2] = t.z; v[3] = t.w;
  } else if constexpr (H == 2) {
    float2 t = *(const float2*)p;
    v[0] = t.x; v[1] = t.y;
  } else {
    v[0] = *p;
  }
}

// ===========================================================================
// bf16 MFMA GEMM: C[n x M] = act(A[n x K] @ Bt^T + bias)
//   128x128 tile, 4 waves x (64x64), BK=64, glds staging w/ XOR swizzle.
//   ALPHA=1: also compute alpha_s/alpha_d = proj-row dot a_src/a_dst per
//   head, fused in epilogue (wave's 64-col range is within ONE head).
// ===========================================================================
template <int ACT, int OBF, int ALPHA>
__global__ __launch_bounds__(256) void mfma_gemm(
    const unsigned short* __restrict__ A, const unsigned short* __restrict__ Bt,
    const float* __restrict__ bias, float* __restrict__ Cf,
    unsigned short* __restrict__ Cb, int n, int K, int M,
    const float* __restrict__ a_s, const float* __restrict__ a_d,
    float* __restrict__ alS, float* __restrict__ alD, int Chead, int H) {
  __shared__ unsigned short As[128 * 64];
  __shared__ unsigned short Bs[128 * 64];

  const int tid = threadIdx.x;
  const int w = tid >> 6, lane = tid & 63;
  const int row0 = blockIdx.x * 128, col0 = blockIdx.y * 128;
  const int lr = lane >> 3, lg = lane & 7;
  const int lm = lane & 15, kg = lane >> 4;
  const int wm = (w >> 1) * 64, wn = (w & 1) * 64;

  f32x4 acc[4][4];
#pragma unroll
  for (int i = 0; i < 4; i++)
#pragma unroll
    for (int j = 0; j < 4; j++) acc[i][j] = {0.f, 0.f, 0.f, 0.f};

  const int swz = (lg ^ lr) << 3;

  for (int k0 = 0; k0 < K; k0 += 64) {
    __syncthreads();
#pragma unroll
    for (int it = 0; it < 4; it++) {
      const int r = w * 32 + it * 8;
      glds16(A + (size_t)(row0 + r + lr) * K + k0 + swz, &As[r * 64]);
      glds16(Bt + (size_t)(col0 + r + lr) * K + k0 + swz, &Bs[r * 64]);
    }
    __syncthreads();

#pragma unroll
    for (int kh = 0; kh < 2; kh++) {
      const int sw = ((kh * 4 + kg) ^ (lm & 7)) << 3;
      short8 aF[4], bF[4];
#pragma unroll
      for (int i = 0; i < 4; i++) {
        aF[i] = *(const short8*)&As[(wm + i * 16 + lm) * 64 + sw];
        bF[i] = *(const short8*)&Bs[(wn + i * 16 + lm) * 64 + sw];
      }
#pragma unroll
      for (int i = 0; i < 4; i++)
#pragma unroll
        for (int j = 0; j < 4; j++)
          acc[i][j] = __builtin_amdgcn_mfma_f32_16x16x32_bf16(
              aF[i], bF[j], acc[i][j], 0, 0, 0);
    }
  }

  const int r4 = kg * 4;
#pragma unroll
  for (int j = 0; j < 4; j++) {
    const int col = col0 + wn + j * 16 + lm;
    const float bv = bias ? bias[col] : 0.f;
#pragma unroll
    for (int i = 0; i < 4; i++) {
#pragma unroll
      for (int r = 0; r < 4; r++) {
        const int row = row0 + wm + i * 16 + r4 + r;
        if (row < n) {
          float v = acc[i][j][r] + bv;
          if (ACT == 1) v = v > 0.f ? v : 0.f;
          if (OBF)
            Cb[(size_t)row * M + col] = f2b(v);
          else
            Cf[(size_t)row * M + col] = v;
        }
      }
    }
  }

  if (ALPHA) {
    // this wave's cols (col0+wn .. +63) lie in one head
    const int h = (col0 + wn) / Chead;
    float asl[4], adl[4];
#pragma unroll
    for (int j = 0; j < 4; j++) {
      asl[j] = a_s[col0 + wn + j * 16 + lm];
      adl[j] = a_d[col0 + wn + j * 16 + lm];
    }
#pragma unroll
    for (int i = 0; i < 4; i++) {
#pragma unroll
      for (int r = 0; r < 4; r++) {
        float ps = 0.f, pd = 0.f;
#pragma unroll
        for (int j = 0; j < 4; j++) {
          ps += acc[i][j][r] * asl[j];
          pd += acc[i][j][r] * adl[j];
        }
#pragma unroll
        for (int off = 1; off < 16; off <<= 1) {
          ps += __shfl_xor(ps, off, 64);
          pd += __shfl_xor(pd, off, 64);
        }
        const int row = row0 + wm + i * 16 + r4 + r;
        if (lm == 0 && row < n) {
          atomicAdd(&alS[(size_t)row * H + h], ps);
          atomicAdd(&alD[(size_t)row * H + h], pd);
        }
      }
    }
  }
}

// ===========================================================================
// Fused head prep: zero deg + zero alpha buffers + convert x fp32->bf16 +
// all 5 weight transposes.  Grid-stride, no syncs.
// ===========================================================================
struct PrepArgs {
  const float* x; unsigned short* xb; long long nx;
  const float* W[5]; unsigned short* Wt[5];
  int K[5], M[5], t0[6];
  int* deg; float* alzero; long long nalz; int N;
};

__global__ __launch_bounds__(256) void fused_prep_kernel(PrepArgs a) {
  const int tid = threadIdx.x, bid = blockIdx.x, nb = gridDim.x;
  const long long gt = (long long)bid * 256 + tid;
  const long long gsz = (long long)nb * 256;
  __shared__ float tt[32][33];

  for (long long i = gt; i < a.N; i += gsz) a.deg[i] = 0;
  for (long long i = gt; i < a.nalz; i += gsz) a.alzero[i] = 0.f;
  for (long long i = gt * 4; i < a.nx; i += gsz * 4) {
    float4 v = *(const float4*)(a.x + i);
    u16x4 u = {f2b(v.x), f2b(v.y), f2b(v.z), f2b(v.w)};
    *(u16x4*)(a.xb + i) = u;
  }
  for (int t = bid; t < a.t0[5]; t += nb) {
    int di = 0;
    while (t >= a.t0[di + 1]) di++;
    const int local = t - a.t0[di];
    const int K = a.K[di], M = a.M[di], mtiles = M / 32;
    const int mb = (local % mtiles) * 32, kb = (local / mtiles) * 32;
    const float* W = a.W[di];
    unsigned short* Wt = a.Wt[di];
    const int tx = tid & 31, ty = tid >> 5;  // 32 x 8
    __syncthreads();
#pragma unroll
    for (int i = 0; i < 4; i++)
      tt[ty + i * 8][tx] = W[(size_t)(kb + ty + i * 8) * M + mb + tx];
    __syncthreads();
#pragma unroll
    for (int i = 0; i < 4; i++)
      Wt[(size_t)(mb + ty + i * 8) * K + kb + tx] = f2b(tt[tx][ty + i * 8]);
  }
}

// ===========================================================================
// CSR chain (dependency-ordered, separate launches)
// ===========================================================================
__global__ void count_deg_kernel(const int* __restrict__ edst,
                                 int* __restrict__ deg, int E, int n) {
  int i = blockIdx.x * blockDim.x + threadIdx.x;
  if (i >= E + n) return;
  int d = (i < E) ? edst[i] : (i - E);
  if ((unsigned)d < (unsigned)n) atomicAdd(&deg[d], 1);
}

__global__ __launch_bounds__(256) void block_reduce_kernel(
    const int* __restrict__ deg, int* __restrict__ bsum, int n) {
  __shared__ int s[256];
  const int t = threadIdx.x, i = blockIdx.x * 256 + t;
  s[t] = (i < n) ? deg[i] : 0;
  __syncthreads();
#pragma unroll
  for (int off = 128; off; off >>= 1) {
    if (t < off) s[t] += s[t + off];
    __syncthreads();
  }
  if (t == 0) bsum[blockIdx.x] = s[0];
}

__global__ __launch_bounds__(256) void scan_bsums_kernel(int* __restrict__ bsum,
                                                         int nb) {
  __shared__ int s[256];
  const int t = threadIdx.x;
  const int v = (t < nb) ? bsum[t] : 0;
  s[t] = v;
  __syncthreads();
#pragma unroll
  for (int off = 1; off < 256; off <<= 1) {
    int a = (t >= off) ? s[t - off] : 0;
    __syncthreads();
    s[t] += a;
    __syncthreads();
  }
  if (t < nb) bsum[t] = s[t] - v;
}

__global__ __launch_bounds__(256) void scan_final_kernel(
    const int* __restrict__ deg, const int* __restrict__ bsumx,
    int* __restrict__ rowptr, int* __restrict__ cursor, int n) {
  __shared__ int s[256];
  const int t = threadIdx.x, i = blockIdx.x * 256 + t;
  const int v = (i < n) ? deg[i] : 0;
  s[t] = v;
  __syncthreads();
#pragma unroll
  for (int off = 1; off < 256; off <<= 1) {
    int a = (t >= off) ? s[t - off] : 0;
    __syncthreads();
    s[t] += a;
    __syncthreads();
  }
  if (i < n) {
    const int base = bsumx[blockIdx.x];
    const int excl = base + s[t] - v;
    rowptr[i] = excl;
    cursor[i] = excl;
    if (i == n - 1) rowptr[n] = base + s[t];
  }
}

__global__ void scatter_kernel(const int* __restrict__ esrc,
                               const int* __restrict__ edst,
                               int* __restrict__ cursor,
                               int* __restrict__ csr_src, int E, int n) {
  int i = blockIdx.x * blockDim.x + threadIdx.x;
  int tot = E + n;
  if (i >= tot) return;
  int s, d;
  if (i < E) { s = esrc[i]; d = edst[i]; } else { s = d = i - E; }
  if ((unsigned)d >= (unsigned)n || (unsigned)s >= (unsigned)n) return;
  int pos = atomicAdd(&cursor[d], 1);
  if (pos < tot) csr_src[pos] = s;
}

// ===========================================================================
// FUSED GAT softmax + aggregation.  Wave per dst.  Phase 1 stages edge
// weights + src ids in per-wave LDS; phase 2 unrolled x4.
// ===========================================================================
template <int H, int C, bool CONCAT, int ACT, int OBF>
__global__ __launch_bounds__(256) void gat_fused_kernel(
    const unsigned short* __restrict__ proj, const float* __restrict__ alpha_s,
    const float* __restrict__ alpha_d, const int* __restrict__ rowptr,
    const int* __restrict__ csr_src, const float* __restrict__ bias,
    void* __restrict__ out, int n) {
  constexpr int HC = H * C;
  constexpr int ROWSPAN = HC / 8;      // lanes covering one row (16 or 32)
  constexpr int EDGES = 64 / ROWSPAN;  // edges in flight (2 or 4)
  constexpr int WLANES = C / 8;        // writer lanes in mean mode

  __shared__ float exs[4][64 * H];
  __shared__ int sids[4][64];

  const int wv = threadIdx.x >> 6;
  const int wid = (blockIdx.x * blockDim.x + threadIdx.x) >> 6;
  const int lane = threadIdx.x & 63;
  if (wid >= n) return;
  const int dst = wid;
  const int eslot = lane / ROWSPAN;
  const int sl = lane % ROWSPAN;    // row slice: flat channels sl*8..sl*8+7
  const int h_lane = (sl * 8) / C;  // head owning this slice
  float* myex = &exs[wv][0];
  int* mysid = &sids[wv][0];

  float adv[H];
  loadH<H>(alpha_d + (size_t)dst * H, adv);
  const int rs = rowptr[dst], re = rowptr[dst + 1];

  float denomp[H];
#pragma unroll
  for (int h = 0; h < H; h++) denomp[h] = 0.f;
  float acc[8];
#pragma unroll
  for (int k = 0; k < 8; k++) acc[k] = 0.f;

  for (int base = rs; base < re; base += 64) {
    const int cnt = min(64, re - base);
    // phase 1: lane-parallel edge weights + src ids -> LDS
    if (lane < cnt) {
      const int s = csr_src[base + lane];
      mysid[lane] = s;
      float as[H];
      loadH<H>(alpha_s + (size_t)s * H, as);
#pragma unroll
      for (int h = 0; h < H; h++) {
        float e = as[h] + adv[h];
        e = e > 0.f ? e : NEG_SLOPE * e;
        const float ex = __expf(e);
        denomp[h] += ex;
        myex[lane * H + h] = ex;
      }
    }
    __builtin_amdgcn_wave_barrier();
    // phase 2: subgroup-parallel accumulation, unrolled x4
    int j = eslot;
    for (; j + 3 * EDGES < cnt; j += 4 * EDGES) {
      int ss[4];
      float ww[4];
      short8 rr[4];
#pragma unroll
      for (int q = 0; q < 4; q++) {
        ss[q] = mysid[j + q * EDGES];
        ww[q] = myex[(j + q * EDGES) * H + h_lane];
      }
#pragma unroll
      for (int q = 0; q < 4; q++)
        rr[q] = *(const short8*)(proj + (size_t)ss[q] * HC + sl * 8);
#pragma unroll
      for (int q = 0; q < 4; q++)
#pragma unroll
        for (int k = 0; k < 8; k++)
          acc[k] += ww[q] * b2f((unsigned short)rr[q][k]);
    }
    for (; j < cnt; j += EDGES) {
      const int s0 = mysid[j];
      const float w0 = myex[j * H + h_lane];
      const short8 r0 = *(const short8*)(proj + (size_t)s0 * HC + sl * 8);
#pragma unroll
      for (int k = 0; k < 8; k++) acc[k] += w0 * b2f((unsigned short)r0[k]);
    }
    __builtin_amdgcn_wave_barrier();
  }

  // full-wave denom reduce; edge-slot acc reduce
#pragma unroll
  for (int off = 32; off; off >>= 1)
#pragma unroll
    for (int h = 0; h < H; h++)
      denomp[h] += __shfl_xor(denomp[h], off, 64);
#pragma unroll
  for (int off = ROWSPAN; off < 64; off <<= 1)
#pragma unroll
    for (int k = 0; k < 8; k++) acc[k] += __shfl_xor(acc[k], off, 64);

  const float inv = 1.f / (denomp[h_lane] + EPS_DEN);
  float v[8];
#pragma unroll
  for (int k = 0; k < 8; k++) v[k] = acc[k] * inv;

  if (!CONCAT && H == 2) {
#pragma unroll
    for (int k = 0; k < 8; k++) v[k] += __shfl_xor(v[k], 16, 64);
  }

  if (CONCAT) {
    if (eslot != 0) return;
    const int c0 = sl * 8;
    float vv[8];
#pragma unroll
    for (int k = 0; k < 8; k++) {
      float t = v[k] + bias[c0 + k];
      if (ACT == 1) t = t > 0.f ? t : (__expf(t) - 1.f);
      vv[k] = t;
    }
    if (OBF) {
      short8 o;
#pragma unroll
      for (int k = 0; k < 8; k++) o[k] = (short)f2b(vv[k]);
      *(short8*)((unsigned short*)out + (size_t)dst * HC + c0) = o;
    } else {
      float* op = (float*)out + (size_t)dst * HC + c0;
      *(float4*)op = make_float4(vv[0], vv[1], vv[2], vv[3]);
      *(float4*)(op + 4) = make_float4(vv[4], vv[5], vv[6], vv[7]);
    }
  } else {
    if (eslot != 0 || sl >= WLANES) return;
    const int c0 = sl * 8;
    const float invH = 1.f / (float)H;
    float vv[8];
#pragma unroll
    for (int k = 0; k < 8; k++) {
      float t = v[k] * invH + bias[c0 + k];
      if (ACT == 1) t = t > 0.f ? t : (__expf(t) - 1.f);
      vv[k] = t;
    }
    if (OBF) {
      short8 o;
#pragma unroll
      for (int k = 0; k < 8; k++) o[k] = (short)f2b(vv[k]);
      *(short8*)((unsigned short*)out + (size_t)dst * C + c0) = o;
    } else {
      float* op = (float*)out + (size_t)dst * C + c0;
      *(float4*)op = make_float4(vv[0], vv[1], vv[2], vv[3]);
      *(float4*)(op + 4) = make_float4(vv[4], vv[5], vv[6], vv[7]);
    }
  }
}

// ===========================================================================
// Host side
// ===========================================================================
extern "C" void kernel_launch(void* const* d_in, const int* in_sizes, int n_in,
                              void* d_out, int out_size, void* d_ws,
                              size_t ws_size, hipStream_t stream) {
  const float* x    = (const float*)d_in[0];
  const int*   ei   = (const int*)d_in[1];
  const float* W1   = (const float*)d_in[2];
  const float* b1   = (const float*)d_in[3];
  const float* W2   = (const float*)d_in[4];
  const float* b2   = (const float*)d_in[5];
  const float* g1W  = (const float*)d_in[6];
  const float* g1as = (const float*)d_in[7];
  const float* g1ad = (const float*)d_in[8];
  const float* g1b  = (const float*)d_in[9];
  const float* g2W  = (const float*)d_in[10];
  const float* g2as = (const float*)d_in[11];
  const float* g2ad = (const float*)d_in[12];
  const float* g2b  = (const float*)d_in[13];
  const float* g3W  = (const float*)d_in[14];
  const float* g3as = (const float*)d_in[15];
  const float* g3ad = (const float*)d_in[16];
  const float* g3b  = (const float*)d_in[17];

  const int N = in_sizes[0] / 256;   // 50000
  const int E = in_sizes[1] / 2;     // 800000
  const int Etot = E + N;
  const int NT = (N + 127) / 128;
  const int NP = NT * 128;
  const int NB = (N + 255) / 256;    // scan chunks (196 <= 256)

  // ---- workspace layout ----
  char* p = (char*)d_ws;
  unsigned short* Pb  = (unsigned short*)p; p += (size_t)NP * 256 * 2;  // bf16 proj
  unsigned short* xb  = (unsigned short*)p; p += (size_t)NP * 256 * 2;  // x / act1b
  unsigned short* h1b = (unsigned short*)p; p += (size_t)NP * 128 * 2;
  unsigned short* h2b = (unsigned short*)p; p += (size_t)NP * 128 * 2;  // h2 / act2b
  unsigned short* W1t = (unsigned short*)p; p += (size_t)128 * 256 * 2;
  unsigned short* W2t = (unsigned short*)p; p += (size_t)128 * 128 * 2;
  unsigned short* g1Wt = (unsigned short*)p; p += (size_t)256 * 128 * 2;
  unsigned short* g2Wt = (unsigned short*)p; p += (size_t)256 * 256 * 2;
  unsigned short* g3Wt = (unsigned short*)p; p += (size_t)128 * 128 * 2;
  // per-layer alpha buffers (atomic-accumulated in GEMM epilogue)
  float* alS1 = (float*)p; p += (size_t)NP * 4 * 4;
  float* alD1 = (float*)p; p += (size_t)NP * 4 * 4;
  float* alS2 = (float*)p; p += (size_t)NP * 2 * 4;
  float* alD2 = (float*)p; p += (size_t)NP * 2 * 4;
  float* alS3 = (float*)p; p += (size_t)NP * 1 * 4;
  float* alD3 = (float*)p; p += (size_t)NP * 1 * 4;
  int* deg    = (int*)p;
  int* rowptr = deg + N;
  int* cursor = rowptr + N + 1;
  int* bsum   = cursor + N;
  int* csrsrc = bsum + 256;

  const int* esrc = ei;
  const int* edst = ei + E;
  unsigned short* act1b = xb;   // reuse after MLP1 consumed xb
  unsigned short* act2b = h2b;  // reuse after GAT1-proj consumed h2b
  const long long nalz = (long long)NP * (4 + 4 + 2 + 2 + 1 + 1);

  // ---- prep: fused head kernel + CSR chain ----
  PrepArgs pa;
  pa.x = x; pa.xb = xb; pa.nx = (long long)N * 256;
  pa.W[0] = W1;  pa.Wt[0] = W1t;  pa.K[0] = 256; pa.M[0] = 128;
  pa.W[1] = W2;  pa.Wt[1] = W2t;  pa.K[1] = 128; pa.M[1] = 128;
  pa.W[2] = g1W; pa.Wt[2] = g1Wt; pa.K[2] = 128; pa.M[2] = 256;
  pa.W[3] = g2W; pa.Wt[3] = g2Wt; pa.K[3] = 256; pa.M[3] = 256;
  pa.W[4] = g3W; pa.Wt[4] = g3Wt; pa.K[4] = 128; pa.M[4] = 128;
  pa.t0[0] = 0;
  for (int i = 0; i < 5; i++)
    pa.t0[i + 1] = pa.t0[i] + (pa.K[i] / 32) * (pa.M[i] / 32);
  pa.deg = deg; pa.alzero = alS1; pa.nalz = nalz; pa.N = N;
  fused_prep_kernel<<<512, 256, 0, stream>>>(pa);

  count_deg_kernel<<<(Etot + 255) / 256, 256, 0, stream>>>(edst, deg, E, N);
  block_reduce_kernel<<<NB, 256, 0, stream>>>(deg, bsum, N);
  scan_bsums_kernel<<<1, 256, 0, stream>>>(bsum, NB);
  scan_final_kernel<<<NB, 256, 0, stream>>>(deg, bsum, rowptr, cursor, N);
  scatter_kernel<<<(Etot + 255) / 256, 256, 0, stream>>>(esrc, edst, cursor,
                                                         csrsrc, E, N);

  // ---- MLP ----
  mfma_gemm<1, 1, 0><<<dim3(NT, 1), 256, 0, stream>>>(
      xb, W1t, b1, nullptr, h1b, N, 256, 128, nullptr, nullptr, nullptr,
      nullptr, 0, 0);
  mfma_gemm<1, 1, 0><<<dim3(NT, 1), 256, 0, stream>>>(
      h1b, W2t, b2, nullptr, h2b, N, 128, 128, nullptr, nullptr, nullptr,
      nullptr, 0, 0);

  // ---- GAT1: 128 -> 4 x 64, concat, ELU ----
  mfma_gemm<0, 1, 1><<<dim3(NT, 2), 256, 0, stream>>>(
      h2b, g1Wt, nullptr, nullptr, Pb, N, 128, 256, g1as, g1ad, alS1, alD1,
      64, 4);
  gat_fused_kernel<4, 64, true, 1, 1><<<(N + 3) / 4, 256, 0, stream>>>(
      Pb, alS1, alD1, rowptr, csrsrc, g1b, act1b, N);

  // ---- GAT2: 256 -> 2 x 128, mean, ELU ----
  mfma_gemm<0, 1, 1><<<dim3(NT, 2), 256, 0, stream>>>(
      act1b, g2Wt, nullptr, nullptr, Pb, N, 256, 256, g2as, g2ad, alS2, alD2,
      128, 2);
  gat_fused_kernel<2, 128, false, 1, 1><<<(N + 3) / 4, 256, 0, stream>>>(
      Pb, alS2, alD2, rowptr, csrsrc, g2b, act2b, N);

  // ---- GAT3: 128 -> 1 x 128, mean, none -> d_out (fp32) ----
  mfma_gemm<0, 1, 1><<<dim3(NT, 1), 256, 0, stream>>>(
      act2b, g3Wt, nullptr, nullptr, Pb, N, 128, 128, g3as, g3ad, alS3, alD3,
      128, 1);
  gat_fused_kernel<1, 128, false, 0, 0><<<(N + 3) / 4, 256, 0, stream>>>(
      Pb, alS3, alD3, rowptr, csrsrc, g3b, d_out, N);
}

// Round 10
// 500.643 us; speedup vs baseline: 1.0519x; 1.0519x over previous
//
#include <hip/hip_runtime.h>
#include <math.h>

// ---------------------------------------------------------------------------
// N=50000 nodes, E=800000 edges (+N self-loops), IN=256, HID=128, OUT=128.
// GEMMs: bf16 MFMA 16x16x32.  MLP1+MLP2 fused in one kernel (h1 via LDS).
// GAT: fused softmax+aggregation (x2 unroll, 32 VGPR config).
// ---------------------------------------------------------------------------

#define NEG_SLOPE 0.2f
#define EPS_DEN 1e-16f

typedef __attribute__((ext_vector_type(8))) short short8;
typedef __attribute__((ext_vector_type(4))) float f32x4;
typedef __attribute__((ext_vector_type(4))) unsigned short u16x4;

__device__ inline unsigned short f2b(float f) {  // RNE float->bf16
  unsigned u = __builtin_bit_cast(unsigned, f);
  unsigned r = (u + 0x7fffu + ((u >> 16) & 1u)) >> 16;
  return (unsigned short)r;
}
__device__ inline float b2f(unsigned short u) {
  return __builtin_bit_cast(float, (unsigned)u << 16);
}

__device__ inline void glds16(const void* g, void* l) {
  __builtin_amdgcn_global_load_lds(
      (const __attribute__((address_space(1))) void*)g,
      (__attribute__((address_space(3))) void*)l, 16, 0, 0);
}

template <int H>
__device__ inline void loadH(const float* p, float* v) {
  if constexpr (H == 4) {
    float4 t = *(const float4*)p;
    v[0] = t.x; v[1] = t.y; v[2] = t.z; v[3] = t.w;
  } else if constexpr (H == 2) {
    float2 t = *(const float2*)p;
    v[0] = t.x; v[1] = t.y;
  } else {
    v[0] = *p;
  }
}

// ===========================================================================
// bf16 MFMA GEMM: C[n x M] = act(A[n x K] @ Bt^T + bias)
//   128x128 tile, 4 waves x (64x64), BK=64, glds staging w/ XOR swizzle.
// ===========================================================================
template <int ACT, int OBF>
__global__ __launch_bounds__(256) void mfma_gemm(
    const unsigned short* __restrict__ A, const unsigned short* __restrict__ Bt,
    const float* __restrict__ bias, float* __restrict__ Cf,
    unsigned short* __restrict__ Cb, int n, int K, int M) {
  __shared__ unsigned short As[128 * 64];
  __shared__ unsigned short Bs[128 * 64];

  const int tid = threadIdx.x;
  const int w = tid >> 6, lane = tid & 63;
  const int row0 = blockIdx.x * 128, col0 = blockIdx.y * 128;
  const int lr = lane >> 3, lg = lane & 7;
  const int lm = lane & 15, kg = lane >> 4;
  const int wm = (w >> 1) * 64, wn = (w & 1) * 64;

  f32x4 acc[4][4];
#pragma unroll
  for (int i = 0; i < 4; i++)
#pragma unroll
    for (int j = 0; j < 4; j++) acc[i][j] = {0.f, 0.f, 0.f, 0.f};

  const int swz = (lg ^ lr) << 3;

  for (int k0 = 0; k0 < K; k0 += 64) {
    __syncthreads();
#pragma unroll
    for (int it = 0; it < 4; it++) {
      const int r = w * 32 + it * 8;
      glds16(A + (size_t)(row0 + r + lr) * K + k0 + swz, &As[r * 64]);
      glds16(Bt + (size_t)(col0 + r + lr) * K + k0 + swz, &Bs[r * 64]);
    }
    __syncthreads();

#pragma unroll
    for (int kh = 0; kh < 2; kh++) {
      const int sw = ((kh * 4 + kg) ^ (lm & 7)) << 3;
      short8 aF[4], bF[4];
#pragma unroll
      for (int i = 0; i < 4; i++) {
        aF[i] = *(const short8*)&As[(wm + i * 16 + lm) * 64 + sw];
        bF[i] = *(const short8*)&Bs[(wn + i * 16 + lm) * 64 + sw];
      }
#pragma unroll
      for (int i = 0; i < 4; i++)
#pragma unroll
        for (int j = 0; j < 4; j++)
          acc[i][j] = __builtin_amdgcn_mfma_f32_16x16x32_bf16(
              aF[i], bF[j], acc[i][j], 0, 0, 0);
    }
  }

  const int r4 = kg * 4;
#pragma unroll
  for (int j = 0; j < 4; j++) {
    const int col = col0 + wn + j * 16 + lm;
    const float bv = bias ? bias[col] : 0.f;
#pragma unroll
    for (int i = 0; i < 4; i++) {
#pragma unroll
      for (int r = 0; r < 4; r++) {
        const int row = row0 + wm + i * 16 + r4 + r;
        if (row < n) {
          float v = acc[i][j][r] + bv;
          if (ACT == 1) v = v > 0.f ? v : 0.f;
          if (OBF)
            Cb[(size_t)row * M + col] = f2b(v);
          else
            Cf[(size_t)row * M + col] = v;
        }
      }
    }
  }
}

// ===========================================================================
// Fused MLP: h2 = relu(relu(x@W1+b1)@W2+b2), one block per 128 rows.
// Phase A: x[128x256] @ W1t^T -> h1 (bf16) into padded LDS [128][136]
// Phase B: h1 (LDS) @ W2t^T -> h2 global bf16.
// Row stride 136 elems (272B): >=16B aligned, <=2-way bank aliasing (free).
// ===========================================================================
__global__ __launch_bounds__(256) void mlp_fused_kernel(
    const unsigned short* __restrict__ X, const unsigned short* __restrict__ W1t,
    const float* __restrict__ b1, const unsigned short* __restrict__ W2t,
    const float* __restrict__ b2, unsigned short* __restrict__ H2, int n) {
  __shared__ unsigned short As[128 * 64];
  __shared__ unsigned short Bs[128 * 64];
  __shared__ unsigned short H1s[128 * 136];

  const int tid = threadIdx.x;
  const int w = tid >> 6, lane = tid & 63;
  const int row0 = blockIdx.x * 128;
  const int lr = lane >> 3, lg = lane & 7;
  const int lm = lane & 15, kg = lane >> 4;
  const int wm = (w >> 1) * 64, wn = (w & 1) * 64;
  const int swz = (lg ^ lr) << 3;
  const int r4 = kg * 4;

  f32x4 acc[4][4];
#pragma unroll
  for (int i = 0; i < 4; i++)
#pragma unroll
    for (int j = 0; j < 4; j++) acc[i][j] = {0.f, 0.f, 0.f, 0.f};

  // ---- phase A: h1 = relu(x @ W1t^T + b1), K=256, M=128 ----
  for (int k0 = 0; k0 < 256; k0 += 64) {
    __syncthreads();
#pragma unroll
    for (int it = 0; it < 4; it++) {
      const int r = w * 32 + it * 8;
      glds16(X + (size_t)(row0 + r + lr) * 256 + k0 + swz, &As[r * 64]);
      glds16(W1t + (size_t)(r + lr) * 256 + k0 + swz, &Bs[r * 64]);
    }
    __syncthreads();
#pragma unroll
    for (int kh = 0; kh < 2; kh++) {
      const int sw = ((kh * 4 + kg) ^ (lm & 7)) << 3;
      short8 aF[4], bF[4];
#pragma unroll
      for (int i = 0; i < 4; i++) {
        aF[i] = *(const short8*)&As[(wm + i * 16 + lm) * 64 + sw];
        bF[i] = *(const short8*)&Bs[(wn + i * 16 + lm) * 64 + sw];
      }
#pragma unroll
      for (int i = 0; i < 4; i++)
#pragma unroll
        for (int j = 0; j < 4; j++)
          acc[i][j] = __builtin_amdgcn_mfma_f32_16x16x32_bf16(
              aF[i], bF[j], acc[i][j], 0, 0, 0);
    }
  }

  // epilogue A -> LDS (bias + relu, bf16)
#pragma unroll
  for (int j = 0; j < 4; j++) {
    const int col = wn + j * 16 + lm;
    const float bv = b1[col];
#pragma unroll
    for (int i = 0; i < 4; i++) {
#pragma unroll
      for (int r = 0; r < 4; r++) {
        const int lrow = wm + i * 16 + r4 + r;
        float v = acc[i][j][r] + bv;
        v = v > 0.f ? v : 0.f;
        H1s[lrow * 136 + col] = f2b(v);
      }
    }
  }
#pragma unroll
  for (int i = 0; i < 4; i++)
#pragma unroll
    for (int j = 0; j < 4; j++) acc[i][j] = {0.f, 0.f, 0.f, 0.f};
  __syncthreads();  // H1s complete before phase B reads

  // ---- phase B: h2 = relu(h1 @ W2t^T + b2), K=128, M=128 ----
  for (int k0 = 0; k0 < 128; k0 += 64) {
    __syncthreads();  // protect Bs reuse
#pragma unroll
    for (int it = 0; it < 4; it++) {
      const int r = w * 32 + it * 8;
      glds16(W2t + (size_t)(r + lr) * 128 + k0 + swz, &Bs[r * 64]);
    }
    __syncthreads();
#pragma unroll
    for (int kh = 0; kh < 2; kh++) {
      const int swB = ((kh * 4 + kg) ^ (lm & 7)) << 3;
      const int kofs = k0 + (kh * 4 + kg) * 8;
      short8 aF[4], bF[4];
#pragma unroll
      for (int i = 0; i < 4; i++) {
        aF[i] = *(const short8*)&H1s[(wm + i * 16 + lm) * 136 + kofs];
        bF[i] = *(const short8*)&Bs[(wn + i * 16 + lm) * 64 + swB];
      }
#pragma unroll
      for (int i = 0; i < 4; i++)
#pragma unroll
        for (int j = 0; j < 4; j++)
          acc[i][j] = __builtin_amdgcn_mfma_f32_16x16x32_bf16(
              aF[i], bF[j], acc[i][j], 0, 0, 0);
    }
  }

  // epilogue B -> global bf16
#pragma unroll
  for (int j = 0; j < 4; j++) {
    const int col = wn + j * 16 + lm;
    const float bv = b2[col];
#pragma unroll
    for (int i = 0; i < 4; i++) {
#pragma unroll
      for (int r = 0; r < 4; r++) {
        const int row = row0 + wm + i * 16 + r4 + r;
        if (row < n) {
          float v = acc[i][j][r] + bv;
          v = v > 0.f ? v : 0.f;
          H2[(size_t)row * 128 + col] = f2b(v);
        }
      }
    }
  }
}

// ===========================================================================
// Fused head prep: zero deg + convert x fp32->bf16 + all 5 weight
// transposes.  Grid-stride, no syncs.
// ===========================================================================
struct PrepArgs {
  const float* x; unsigned short* xb; long long nx;
  const float* W[5]; unsigned short* Wt[5];
  int K[5], M[5], t0[6];
  int* deg; int N;
};

__global__ __launch_bounds__(256) void fused_prep_kernel(PrepArgs a) {
  const int tid = threadIdx.x, bid = blockIdx.x, nb = gridDim.x;
  const long long gt = (long long)bid * 256 + tid;
  const long long gsz = (long long)nb * 256;
  __shared__ float tt[32][33];

  for (long long i = gt; i < a.N; i += gsz) a.deg[i] = 0;
  for (long long i = gt * 4; i < a.nx; i += gsz * 4) {
    float4 v = *(const float4*)(a.x + i);
    u16x4 u = {f2b(v.x), f2b(v.y), f2b(v.z), f2b(v.w)};
    *(u16x4*)(a.xb + i) = u;
  }
  for (int t = bid; t < a.t0[5]; t += nb) {
    int di = 0;
    while (t >= a.t0[di + 1]) di++;
    const int local = t - a.t0[di];
    const int K = a.K[di], M = a.M[di], mtiles = M / 32;
    const int mb = (local % mtiles) * 32, kb = (local / mtiles) * 32;
    const float* W = a.W[di];
    unsigned short* Wt = a.Wt[di];
    const int tx = tid & 31, ty = tid >> 5;  // 32 x 8
    __syncthreads();
#pragma unroll
    for (int i = 0; i < 4; i++)
      tt[ty + i * 8][tx] = W[(size_t)(kb + ty + i * 8) * M + mb + tx];
    __syncthreads();
#pragma unroll
    for (int i = 0; i < 4; i++)
      Wt[(size_t)(mb + ty + i * 8) * K + kb + tx] = f2b(tt[tx][ty + i * 8]);
  }
}

// ===========================================================================
// CSR chain (dependency-ordered, separate launches)
// ===========================================================================
__global__ void count_deg_kernel(const int* __restrict__ edst,
                                 int* __restrict__ deg, int E, int n) {
  int i = blockIdx.x * blockDim.x + threadIdx.x;
  if (i >= E + n) return;
  int d = (i < E) ? edst[i] : (i - E);
  if ((unsigned)d < (unsigned)n) atomicAdd(&deg[d], 1);
}

__global__ __launch_bounds__(256) void block_reduce_kernel(
    const int* __restrict__ deg, int* __restrict__ bsum, int n) {
  __shared__ int s[256];
  const int t = threadIdx.x, i = blockIdx.x * 256 + t;
  s[t] = (i < n) ? deg[i] : 0;
  __syncthreads();
#pragma unroll
  for (int off = 128; off; off >>= 1) {
    if (t < off) s[t] += s[t + off];
    __syncthreads();
  }
  if (t == 0) bsum[blockIdx.x] = s[0];
}

__global__ __launch_bounds__(256) void scan_bsums_kernel(int* __restrict__ bsum,
                                                         int nb) {
  __shared__ int s[256];
  const int t = threadIdx.x;
  const int v = (t < nb) ? bsum[t] : 0;
  s[t] = v;
  __syncthreads();
#pragma unroll
  for (int off = 1; off < 256; off <<= 1) {
    int a = (t >= off) ? s[t - off] : 0;
    __syncthreads();
    s[t] += a;
    __syncthreads();
  }
  if (t < nb) bsum[t] = s[t] - v;
}

__global__ __launch_bounds__(256) void scan_final_kernel(
    const int* __restrict__ deg, const int* __restrict__ bsumx,
    int* __restrict__ rowptr, int* __restrict__ cursor, int n) {
  __shared__ int s[256];
  const int t = threadIdx.x, i = blockIdx.x * 256 + t;
  const int v = (i < n) ? deg[i] : 0;
  s[t] = v;
  __syncthreads();
#pragma unroll
  for (int off = 1; off < 256; off <<= 1) {
    int a = (t >= off) ? s[t - off] : 0;
    __syncthreads();
    s[t] += a;
    __syncthreads();
  }
  if (i < n) {
    const int base = bsumx[blockIdx.x];
    const int excl = base + s[t] - v;
    rowptr[i] = excl;
    cursor[i] = excl;
    if (i == n - 1) rowptr[n] = base + s[t];
  }
}

__global__ void scatter_kernel(const int* __restrict__ esrc,
                               const int* __restrict__ edst,
                               int* __restrict__ cursor,
                               int* __restrict__ csr_src, int E, int n) {
  int i = blockIdx.x * blockDim.x + threadIdx.x;
  int tot = E + n;
  if (i >= tot) return;
  int s, d;
  if (i < E) { s = esrc[i]; d = edst[i]; } else { s = d = i - E; }
  if ((unsigned)d >= (unsigned)n || (unsigned)s >= (unsigned)n) return;
  int pos = atomicAdd(&cursor[d], 1);
  if (pos < tot) csr_src[pos] = s;
}

// ===========================================================================
// Per-node attention logits from bf16 proj (wave per node)
// ===========================================================================
template <int H, int C>
__global__ __launch_bounds__(256) void alpha_kernel(
    const unsigned short* __restrict__ proj, const float* __restrict__ a_s,
    const float* __restrict__ a_d, float* __restrict__ alpha_s,
    float* __restrict__ alpha_d, int n) {
  constexpr int HC = H * C;
  constexpr int GL = C / 4;
  const int wid = (blockIdx.x * blockDim.x + threadIdx.x) >> 6;
  const int lane = threadIdx.x & 63;
  if (wid >= n) return;
  const int c0 = lane * 4;
  float ps = 0.f, pd = 0.f;
  if (c0 < HC) {
    u16x4 raw = *(const u16x4*)(proj + (size_t)wid * HC + c0);
    float4 as = *(const float4*)(a_s + c0);
    float4 ad = *(const float4*)(a_d + c0);
    float f0 = b2f(raw.x), f1 = b2f(raw.y), f2 = b2f(raw.z), f3 = b2f(raw.w);
    ps = f0 * as.x + f1 * as.y + f2 * as.z + f3 * as.w;
    pd = f0 * ad.x + f1 * ad.y + f2 * ad.z + f3 * ad.w;
  }
#pragma unroll
  for (int off = 1; off < GL; off <<= 1) {
    ps += __shfl_xor(ps, off, 64);
    pd += __shfl_xor(pd, off, 64);
  }
  if (c0 < HC && (lane % GL) == 0) {
    int h = c0 / C;
    alpha_s[(size_t)wid * H + h] = ps;
    alpha_d[(size_t)wid * H + h] = pd;
  }
}

// ===========================================================================
// FUSED GAT softmax + aggregation.  Wave per dst.  Phase 1 stages edge
// weights + src ids in per-wave LDS; phase 2 unrolled x2 (32-VGPR config).
// ===========================================================================
template <int H, int C, bool CONCAT, int ACT, int OBF>
__global__ __launch_bounds__(256) void gat_fused_kernel(
    const unsigned short* __restrict__ proj, const float* __restrict__ alpha_s,
    const float* __restrict__ alpha_d, const int* __restrict__ rowptr,
    const int* __restrict__ csr_src, const float* __restrict__ bias,
    void* __restrict__ out, int n) {
  constexpr int HC = H * C;
  constexpr int ROWSPAN = HC / 8;      // lanes covering one row (16 or 32)
  constexpr int EDGES = 64 / ROWSPAN;  // edges in flight (2 or 4)
  constexpr int WLANES = C / 8;        // writer lanes in mean mode

  __shared__ float exs[4][64 * H];
  __shared__ int sids[4][64];

  const int wv = threadIdx.x >> 6;
  const int wid = (blockIdx.x * blockDim.x + threadIdx.x) >> 6;
  const int lane = threadIdx.x & 63;
  if (wid >= n) return;
  const int dst = wid;
  const int eslot = lane / ROWSPAN;
  const int sl = lane % ROWSPAN;    // row slice: flat channels sl*8..sl*8+7
  const int h_lane = (sl * 8) / C;  // head owning this slice
  float* myex = &exs[wv][0];
  int* mysid = &sids[wv][0];

  float adv[H];
  loadH<H>(alpha_d + (size_t)dst * H, adv);
  const int rs = rowptr[dst], re = rowptr[dst + 1];

  float denomp[H];
#pragma unroll
  for (int h = 0; h < H; h++) denomp[h] = 0.f;
  float acc[8];
#pragma unroll
  for (int k = 0; k < 8; k++) acc[k] = 0.f;

  for (int base = rs; base < re; base += 64) {
    const int cnt = min(64, re - base);
    // phase 1: lane-parallel edge weights + src ids -> LDS
    if (lane < cnt) {
      const int s = csr_src[base + lane];
      mysid[lane] = s;
      float as[H];
      loadH<H>(alpha_s + (size_t)s * H, as);
#pragma unroll
      for (int h = 0; h < H; h++) {
        float e = as[h] + adv[h];
        e = e > 0.f ? e : NEG_SLOPE * e;
        const float ex = __expf(e);
        denomp[h] += ex;
        myex[lane * H + h] = ex;
      }
    }
    __builtin_amdgcn_wave_barrier();
    // phase 2: subgroup-parallel accumulation, unrolled x2
    int j = eslot;
    for (; j + EDGES < cnt; j += 2 * EDGES) {
      const int s0 = mysid[j];
      const int s1 = mysid[j + EDGES];
      const float w0 = myex[j * H + h_lane];
      const float w1 = myex[(j + EDGES) * H + h_lane];
      const short8 r0 = *(const short8*)(proj + (size_t)s0 * HC + sl * 8);
      const short8 r1 = *(const short8*)(proj + (size_t)s1 * HC + sl * 8);
#pragma unroll
      for (int k = 0; k < 8; k++) acc[k] += w0 * b2f((unsigned short)r0[k]);
#pragma unroll
      for (int k = 0; k < 8; k++) acc[k] += w1 * b2f((unsigned short)r1[k]);
    }
    for (; j < cnt; j += EDGES) {
      const int s0 = mysid[j];
      const float w0 = myex[j * H + h_lane];
      const short8 r0 = *(const short8*)(proj + (size_t)s0 * HC + sl * 8);
#pragma unroll
      for (int k = 0; k < 8; k++) acc[k] += w0 * b2f((unsigned short)r0[k]);
    }
    __builtin_amdgcn_wave_barrier();
  }

  // full-wave denom reduce; edge-slot acc reduce
#pragma unroll
  for (int off = 32; off; off >>= 1)
#pragma unroll
    for (int h = 0; h < H; h++)
      denomp[h] += __shfl_xor(denomp[h], off, 64);
#pragma unroll
  for (int off = ROWSPAN; off < 64; off <<= 1)
#pragma unroll
    for (int k = 0; k < 8; k++) acc[k] += __shfl_xor(acc[k], off, 64);

  const float inv = 1.f / (denomp[h_lane] + EPS_DEN);
  float v[8];
#pragma unroll
  for (int k = 0; k < 8; k++) v[k] = acc[k] * inv;

  if (!CONCAT && H == 2) {
#pragma unroll
    for (int k = 0; k < 8; k++) v[k] += __shfl_xor(v[k], 16, 64);
  }

  if (CONCAT) {
    if (eslot != 0) return;
    const int c0 = sl * 8;
    float vv[8];
#pragma unroll
    for (int k = 0; k < 8; k++) {
      float t = v[k] + bias[c0 + k];
      if (ACT == 1) t = t > 0.f ? t : (__expf(t) - 1.f);
      vv[k] = t;
    }
    if (OBF) {
      short8 o;
#pragma unroll
      for (int k = 0; k < 8; k++) o[k] = (short)f2b(vv[k]);
      *(short8*)((unsigned short*)out + (size_t)dst * HC + c0) = o;
    } else {
      float* op = (float*)out + (size_t)dst * HC + c0;
      *(float4*)op = make_float4(vv[0], vv[1], vv[2], vv[3]);
      *(float4*)(op + 4) = make_float4(vv[4], vv[5], vv[6], vv[7]);
    }
  } else {
    if (eslot != 0 || sl >= WLANES) return;
    const int c0 = sl * 8;
    const float invH = 1.f / (float)H;
    float vv[8];
#pragma unroll
    for (int k = 0; k < 8; k++) {
      float t = v[k] * invH + bias[c0 + k];
      if (ACT == 1) t = t > 0.f ? t : (__expf(t) - 1.f);
      vv[k] = t;
    }
    if (OBF) {
      short8 o;
#pragma unroll
      for (int k = 0; k < 8; k++) o[k] = (short)f2b(vv[k]);
      *(short8*)((unsigned short*)out + (size_t)dst * C + c0) = o;
    } else {
      float* op = (float*)out + (size_t)dst * C + c0;
      *(float4*)op = make_float4(vv[0], vv[1], vv[2], vv[3]);
      *(float4*)(op + 4) = make_float4(vv[4], vv[5], vv[6], vv[7]);
    }
  }
}

// ===========================================================================
// Host side
// ===========================================================================
extern "C" void kernel_launch(void* const* d_in, const int* in_sizes, int n_in,
                              void* d_out, int out_size, void* d_ws,
                              size_t ws_size, hipStream_t stream) {
  const float* x    = (const float*)d_in[0];
  const int*   ei   = (const int*)d_in[1];
  const float* W1   = (const float*)d_in[2];
  const float* b1   = (const float*)d_in[3];
  const float* W2   = (const float*)d_in[4];
  const float* b2   = (const float*)d_in[5];
  const float* g1W  = (const float*)d_in[6];
  const float* g1as = (const float*)d_in[7];
  const float* g1ad = (const float*)d_in[8];
  const float* g1b  = (const float*)d_in[9];
  const float* g2W  = (const float*)d_in[10];
  const float* g2as = (const float*)d_in[11];
  const float* g2ad = (const float*)d_in[12];
  const float* g2b  = (const float*)d_in[13];
  const float* g3W  = (const float*)d_in[14];
  const float* g3as = (const float*)d_in[15];
  const float* g3ad = (const float*)d_in[16];
  const float* g3b  = (const float*)d_in[17];

  const int N = in_sizes[0] / 256;   // 50000
  const int E = in_sizes[1] / 2;     // 800000
  const int Etot = E + N;
  const int NT = (N + 127) / 128;
  const int NP = NT * 128;
  const int NB = (N + 255) / 256;    // scan chunks (196 <= 256)

  // ---- workspace layout ----
  char* p = (char*)d_ws;
  unsigned short* Pb  = (unsigned short*)p; p += (size_t)NP * 256 * 2;  // bf16 proj
  unsigned short* xb  = (unsigned short*)p; p += (size_t)NP * 256 * 2;  // x / act1b
  unsigned short* h2b = (unsigned short*)p; p += (size_t)NP * 128 * 2;  // h2 / act2b
  unsigned short* W1t = (unsigned short*)p; p += (size_t)128 * 256 * 2;
  unsigned short* W2t = (unsigned short*)p; p += (size_t)128 * 128 * 2;
  unsigned short* g1Wt = (unsigned short*)p; p += (size_t)256 * 128 * 2;
  unsigned short* g2Wt = (unsigned short*)p; p += (size_t)256 * 256 * 2;
  unsigned short* g3Wt = (unsigned short*)p; p += (size_t)128 * 128 * 2;
  float* alS  = (float*)p; p += (size_t)N * 4 * 4;
  float* alD  = (float*)p; p += (size_t)N * 4 * 4;
  int* deg    = (int*)p;
  int* rowptr = deg + N;
  int* cursor = rowptr + N + 1;
  int* bsum   = cursor + N;
  int* csrsrc = bsum + 256;

  const int* esrc = ei;
  const int* edst = ei + E;
  unsigned short* act1b = xb;   // reuse after MLP consumed xb
  unsigned short* act2b = h2b;  // reuse after GAT1-proj consumed h2b

  // ---- prep: fused head kernel + CSR chain ----
  PrepArgs pa;
  pa.x = x; pa.xb = xb; pa.nx = (long long)N * 256;
  pa.W[0] = W1;  pa.Wt[0] = W1t;  pa.K[0] = 256; pa.M[0] = 128;
  pa.W[1] = W2;  pa.Wt[1] = W2t;  pa.K[1] = 128; pa.M[1] = 128;
  pa.W[2] = g1W; pa.Wt[2] = g1Wt; pa.K[2] = 128; pa.M[2] = 256;
  pa.W[3] = g2W; pa.Wt[3] = g2Wt; pa.K[3] = 256; pa.M[3] = 256;
  pa.W[4] = g3W; pa.Wt[4] = g3Wt; pa.K[4] = 128; pa.M[4] = 128;
  pa.t0[0] = 0;
  for (int i = 0; i < 5; i++)
    pa.t0[i + 1] = pa.t0[i] + (pa.K[i] / 32) * (pa.M[i] / 32);
  pa.deg = deg; pa.N = N;
  fused_prep_kernel<<<512, 256, 0, stream>>>(pa);

  count_deg_kernel<<<(Etot + 255) / 256, 256, 0, stream>>>(edst, deg, E, N);
  block_reduce_kernel<<<NB, 256, 0, stream>>>(deg, bsum, N);
  scan_bsums_kernel<<<1, 256, 0, stream>>>(bsum, NB);
  scan_final_kernel<<<NB, 256, 0, stream>>>(deg, bsum, rowptr, cursor, N);
  scatter_kernel<<<(Etot + 255) / 256, 256, 0, stream>>>(esrc, edst, cursor,
                                                         csrsrc, E, N);

  // ---- fused MLP: x -> h2 (one kernel) ----
  mlp_fused_kernel<<<NT, 256, 0, stream>>>(xb, W1t, b1, W2t, b2, h2b, N);

  // ---- GAT1: 128 -> 4 x 64, concat, ELU ----
  mfma_gemm<0, 1><<<dim3(NT, 2), 256, 0, stream>>>(h2b, g1Wt, nullptr, nullptr,
                                                   Pb, N, 128, 256);
  alpha_kernel<4, 64><<<(N + 3) / 4, 256, 0, stream>>>(Pb, g1as, g1ad, alS,
                                                       alD, N);
  gat_fused_kernel<4, 64, true, 1, 1><<<(N + 3) / 4, 256, 0, stream>>>(
      Pb, alS, alD, rowptr, csrsrc, g1b, act1b, N);

  // ---- GAT2: 256 -> 2 x 128, mean, ELU ----
  mfma_gemm<0, 1><<<dim3(NT, 2), 256, 0, stream>>>(act1b, g2Wt, nullptr,
                                                   nullptr, Pb, N, 256, 256);
  alpha_kernel<2, 128><<<(N + 3) / 4, 256, 0, stream>>>(Pb, g2as, g2ad, alS,
                                                        alD, N);
  gat_fused_kernel<2, 128, false, 1, 1><<<(N + 3) / 4, 256, 0, stream>>>(
      Pb, alS, alD, rowptr, csrsrc, g2b, act2b, N);

  // ---- GAT3: 128 -> 1 x 128, mean, none -> d_out (fp32) ----
  mfma_gemm<0, 1><<<dim3(NT, 1), 256, 0, stream>>>(act2b, g3Wt, nullptr,
                                                   nullptr, Pb, N, 128, 128);
  alpha_kernel<1, 128><<<(N + 3) / 4, 256, 0, stream>>>(Pb, g3as, g3ad, alS,
                                                        alD, N);
  gat_fused_kernel<1, 128, false, 0, 0><<<(N + 3) / 4, 256, 0, stream>>>(
      Pb, alS, alD, rowptr, csrsrc, g3b, d_out, N);
}